// Round 23
// baseline (48.085 us; speedup 1.0000x reference)
//
#include <hip/hip_runtime.h>

#define DIMV 16
#define NSTEP 4095      // 4096 - 1 increments
#define NC 64           // chunks
#define TSTEP 64        // chunk length
#define SIG13 4368      // 16 + 256 + 4096
#define L4 65536        // 16^4

// 16-wide register vector as explicit float4s — never runtime-indexed (rule #20).
struct V16 { float4 a, b, c, d; };

#define EACH(OP) OP(a,x) OP(a,y) OP(a,z) OP(a,w) OP(b,x) OP(b,y) OP(b,z) OP(b,w) \
                 OP(c,x) OP(c,y) OP(c,z) OP(c,w) OP(d,x) OP(d,y) OP(d,z) OP(d,w)

__device__ inline V16 ldv16(const float* p) {
    const float4* q = reinterpret_cast<const float4*>(p);
    V16 v; v.a = q[0]; v.b = q[1]; v.c = q[2]; v.d = q[3]; return v;
}
__device__ inline void stv16(float* p, const V16& v) {
    float4* q = reinterpret_cast<float4*>(p);
    q[0] = v.a; q[1] = v.b; q[2] = v.c; q[3] = v.d;
}
__device__ inline V16 zerov16() {
    V16 v; v.a = v.b = v.c = v.d = make_float4(0.f, 0.f, 0.f, 0.f); return v;
}

// select float4 quad (j = 4h..4h+3) of a V16 — uniform switch (h = blockIdx.y)
__device__ __forceinline__ float4 pick_quad(const V16& v, int h) {
    switch (h) {
        case 0:  return v.a;
        case 1:  return v.b;
        case 2:  return v.c;
        default: return v.d;
    }
}

// ===== K1: chunk-LOCAL level-4 scan (from zero), j-QUAD blocks =====
// block (cb, h): chunk cb, j-quad (4h..4h+3). Stages the x-chunk into LDS,
// computes dx in registers, runs the 64-step local recurrence with 4 j-lanes
// per thread. Each block writes its own quarter of the L3 chunk-sig (A3q);
// h==0 also writes L1/L2. DS instrs: 6/step (dj4 comes free from dxv).
template <bool ATOMIC>
__global__ __launch_bounds__(256, 1) void k_local4(const float* __restrict__ x,
                                                   float* __restrict__ chunk_sig,
                                                   float* __restrict__ dst) {
    __shared__ float sx[(TSTEP + 1) * DIMV];   // 4.16 KB
    const int cb = blockIdx.x;   // 0..NC-1
    const int h = blockIdx.y;    // 0..3 : j-quad
    const int t = threadIdx.x;
    const int ia = t >> 4, ib = t & 15;

    const int s0 = cb * TSTEP;
    const int s1 = (s0 + TSTEP < NSTEP) ? (s0 + TSTEP) : NSTEP;
    const int nrow = s1 - s0;                  // 64 (63 for last chunk)

    {
        const float4* src = reinterpret_cast<const float4*>(x + (size_t)s0 * DIMV);
        float4* sd4 = reinterpret_cast<float4*>(sx);
        const int nslot = (nrow + 1) * (DIMV / 4);   // <= 260
        if (t < nslot) sd4[t] = src[t];
        int slot2 = t + 256;
        if (slot2 < nslot) sd4[slot2] = src[slot2];
    }
    __syncthreads();

    float A1a = 0.f, A2 = 0.f;
    float4 A3q = make_float4(0.f, 0.f, 0.f, 0.f);
    V16 ac0 = zerov16(), ac1 = zerov16(), ac2 = zerov16(), ac3 = zerov16();

    V16 xprev = ldv16(sx);
    float xpa = sx[ia], xpb = sx[ib];

    for (int si = 0; si < nrow; ++si) {
        const float* nr = sx + (si + 1) * DIMV;
        V16 xc = ldv16(nr);                    // 4x ds_read_b128 (broadcast)
        float xca = nr[ia];                    // ds_read_b32
        float xcb = nr[ib];                    // ds_read_b32

        V16 dxv;
#define SB(Q,C) dxv.Q.C = xc.Q.C - xprev.Q.C;
        EACH(SB)
#undef SB
        float dxa = xca - xpa;
        float dxb = xcb - xpb;
        float4 dj = pick_quad(dxv, h);         // free: uniform select of dxv

        float U2 = fmaf(dxb, fmaf(dxa, 1.f/24.f, A1a * (1.f/6.f)), 0.5f * A2);
        float V2 = fmaf(dxb, fmaf(dxa, 1.f/6.f, A1a * 0.5f), A2);
        float h2 = fmaf(dxa, 0.5f, A1a);
        float u30 = fmaf(dj.x, U2, A3q.x);
        float u31 = fmaf(dj.y, U2, A3q.y);
        float u32 = fmaf(dj.z, U2, A3q.z);
        float u33 = fmaf(dj.w, U2, A3q.w);
#define AC(Q,C) { ac0.Q.C = fmaf(u30, dxv.Q.C, ac0.Q.C); \
                  ac1.Q.C = fmaf(u31, dxv.Q.C, ac1.Q.C); \
                  ac2.Q.C = fmaf(u32, dxv.Q.C, ac2.Q.C); \
                  ac3.Q.C = fmaf(u33, dxv.Q.C, ac3.Q.C); }
        EACH(AC)
#undef AC
        A3q.x = fmaf(dj.x, V2, A3q.x);
        A3q.y = fmaf(dj.y, V2, A3q.y);
        A3q.z = fmaf(dj.z, V2, A3q.z);
        A3q.w = fmaf(dj.w, V2, A3q.w);
        A2 = fmaf(dxb, h2, A2);
        A1a += dxa;

        xprev = xc; xpa = xca; xpb = xcb;
    }

    if (ATOMIC) {
        float* o = dst + t * 256 + (h * 4) * 16;
#define STA(Q,C,K) { atomicAdd(o + (K),      ac0.Q.C); atomicAdd(o + 16 + (K), ac1.Q.C); \
                     atomicAdd(o + 32 + (K), ac2.Q.C); atomicAdd(o + 48 + (K), ac3.Q.C); }
        STA(a,x,0) STA(a,y,1) STA(a,z,2) STA(a,w,3)
        STA(b,x,4) STA(b,y,5) STA(b,z,6) STA(b,w,7)
        STA(c,x,8) STA(c,y,9) STA(c,z,10) STA(c,w,11)
        STA(d,x,12) STA(d,y,13) STA(d,z,14) STA(d,w,15)
#undef STA
    } else {
        float* o = dst + (size_t)cb * L4 + t * 256 + (h * 4) * 16;
        stv16(o, ac0);
        stv16(o + 16, ac1);
        stv16(o + 32, ac2);
        stv16(o + 48, ac3);
    }

    // chunk-sig: block h owns L3[t][4h..4h+3] = A3q; h==0 writes L1/L2
    float* o = chunk_sig + (size_t)cb * SIG13;
    *reinterpret_cast<float4*>(o + 272 + t * 16 + h * 4) = A3q;
    if (h == 0) {
        if (ib == 0) o[ia] = A1a;
        o[16 + t] = A2;
    }
}

// ===== K2: fused prefix-cascade + correction + reduce (R22-proven) =====
template <bool HAVE_PART>
__global__ __launch_bounds__(256, 1) void k_fuse(const float* __restrict__ partials,
                                                 const float* __restrict__ chunk_sig,
                                                 float* __restrict__ out13,
                                                 float* __restrict__ out4) {
    const int a = blockIdx.x;      // 0..15
    const int b = blockIdx.y;      // 0..15
    const int t = threadIdx.x;     // j*16 + d
    const int j = t >> 4, d = t & 15;
    const int e = a * 4096 + b * 256 + t;

    float P1 = 0.f, P2 = 0.f, P3 = 0.f, acc = 0.f;

#define DECL(J) float s1a_##J, s1b_##J, s1j_##J, l2ab_##J, l2bj_##J, l2jd_##J, \
                      l3abj_##J, l3bjd_##J, l1d_##J, pt_##J;
    DECL(0) DECL(1) DECL(2) DECL(3)
#undef DECL
#define PLOAD(J, C) { int cc = (C) < NC ? (C) : NC - 1; \
    const float* B = chunk_sig + (size_t)cc * SIG13; \
    s1a_##J = B[a]; s1b_##J = B[b]; s1j_##J = B[j]; l1d_##J = B[d]; \
    l2ab_##J = B[16 + a * 16 + b]; \
    l2bj_##J = B[16 + b * 16 + j]; \
    l2jd_##J = B[16 + t]; \
    l3abj_##J = B[272 + a * 256 + b * 16 + j]; \
    l3bjd_##J = B[272 + b * 256 + t]; \
    pt_##J = HAVE_PART ? partials[(size_t)cc * L4 + e] : 0.f; }
    PLOAD(0, 0) PLOAD(1, 1) PLOAD(2, 2) PLOAD(3, 3)

    for (int c0 = 0; c0 < NC; c0 += 4) {
#define PSTEP(J) { int c = c0 + J; \
        acc += pt_##J + fmaf(P1, l3bjd_##J, fmaf(P2, l2jd_##J, P3 * l1d_##J)); \
        P3 += l3abj_##J + fmaf(P1, l2bj_##J, P2 * s1j_##J); \
        P2 += l2ab_##J + P1 * s1b_##J; \
        P1 += s1a_##J; \
        PLOAD(J, c + 4) }
        PSTEP(0) PSTEP(1) PSTEP(2) PSTEP(3)
#undef PSTEP
    }
#undef PLOAD

    if (b == 0 && t == 0) out13[a] = P1;
    if (t == 0) out13[16 + a * 16 + b] = P2;
    if (d == 0) out13[272 + a * 256 + b * 16 + j] = P3;

    if (HAVE_PART) out4[e] = acc;
    else           out4[e] += acc;   // local-L4 already atomically accumulated
}

extern "C" void kernel_launch(void* const* d_in, const int* in_sizes, int n_in,
                              void* d_out, int out_size, void* d_ws, size_t ws_size,
                              hipStream_t stream) {
    const float* x = (const float*)d_in[0];
    float* out = (float*)d_out;
    float* ws = (float*)d_ws;

    float* chunk_sig = ws;                               // NC * SIG13
    float* partials = chunk_sig + (size_t)NC * SIG13;    // NC * L4
    const size_t need_bytes =
        ((size_t)NC * SIG13 + (size_t)NC * L4) * sizeof(float);

    if (ws_size >= need_bytes) {
        k_local4<false><<<dim3(NC, 4), dim3(256), 0, stream>>>(x, chunk_sig, partials);
        k_fuse<true><<<dim3(16, 16), dim3(256), 0, stream>>>(partials, chunk_sig,
                                                             out, out + SIG13);
    } else {
        hipMemsetAsync(out + SIG13, 0, (size_t)L4 * sizeof(float), stream);
        k_local4<true><<<dim3(NC, 4), dim3(256), 0, stream>>>(x, chunk_sig, out + SIG13);
        k_fuse<false><<<dim3(16, 16), dim3(256), 0, stream>>>(nullptr, chunk_sig,
                                                              out, out + SIG13);
    }
}

// Round 24
// 43.549 us; speedup vs baseline: 1.1042x; 1.1042x over previous
//
#include <hip/hip_runtime.h>

#define DIMV 16
#define NSTEP 4095      // 4096 - 1 increments
#define NC 64           // chunks
#define TSTEP 64        // chunk length
#define SIG13 4368      // 16 + 256 + 4096
#define L4 65536        // 16^4

// 16-wide register vector as explicit float4s — never runtime-indexed (rule #20).
struct V16 { float4 a, b, c, d; };

#define EACH(OP) OP(a,x) OP(a,y) OP(a,z) OP(a,w) OP(b,x) OP(b,y) OP(b,z) OP(b,w) \
                 OP(c,x) OP(c,y) OP(c,z) OP(c,w) OP(d,x) OP(d,y) OP(d,z) OP(d,w)

__device__ inline V16 ldv16(const float* p) {
    const float4* q = reinterpret_cast<const float4*>(p);
    V16 v; v.a = q[0]; v.b = q[1]; v.c = q[2]; v.d = q[3]; return v;
}
__device__ inline void stv16(float* p, const V16& v) {
    float4* q = reinterpret_cast<float4*>(p);
    q[0] = v.a; q[1] = v.b; q[2] = v.c; q[3] = v.d;
}
__device__ inline V16 zerov16() {
    V16 v; v.a = v.b = v.c = v.d = make_float4(0.f, 0.f, 0.f, 0.f); return v;
}

// ===== K1: chunk-LOCAL level-4 scan (from zero; no dependencies) =====
// (R22-proven verbatim.) block (cb, h): chunk cb, j-pair (2h, 2h+1). Stages the
// x-chunk into LDS, computes dx in registers, runs the 64-step local recurrence.
// h==0 blocks also write the levels-1..3 chunk signature.
template <bool ATOMIC>
__global__ __launch_bounds__(256, 1) void k_local4(const float* __restrict__ x,
                                                   float* __restrict__ chunk_sig,
                                                   float* __restrict__ dst) {
    __shared__ float sx[(TSTEP + 1) * DIMV];   // 4.16 KB
    const int cb = blockIdx.x;   // 0..NC-1
    const int h = blockIdx.y;    // 0..7 : j-pair
    const int t = threadIdx.x;
    const int ia = t >> 4, ib = t & 15;

    const int s0 = cb * TSTEP;
    const int s1 = (s0 + TSTEP < NSTEP) ? (s0 + TSTEP) : NSTEP;
    const int nrow = s1 - s0;                  // 64 (63 for last chunk)

    {
        const float4* src = reinterpret_cast<const float4*>(x + (size_t)s0 * DIMV);
        float4* sd4 = reinterpret_cast<float4*>(sx);
        const int nslot = (nrow + 1) * (DIMV / 4);   // <= 260
        if (t < nslot) sd4[t] = src[t];
        int slot2 = t + 256;
        if (slot2 < nslot) sd4[slot2] = src[slot2];
    }
    __syncthreads();

    float A1a = 0.f, A2 = 0.f;
    float2 A3p = make_float2(0.f, 0.f);
    V16 A3f = zerov16();                       // full level-3 (used when h==0)
    V16 ac0 = zerov16(), ac1 = zerov16();

    V16 xprev = ldv16(sx);
    float xpa = sx[ia], xpb = sx[ib];
    float2 xpj = *reinterpret_cast<const float2*>(sx + 2 * h);

    for (int si = 0; si < nrow; ++si) {
        const float* nr = sx + (si + 1) * DIMV;
        V16 xc = ldv16(nr);                    // wave-uniform -> LDS broadcast
        float xca = nr[ia];
        float xcb = nr[ib];
        float2 xcj = *reinterpret_cast<const float2*>(nr + 2 * h);

        V16 dxv;
#define SB(Q,C) dxv.Q.C = xc.Q.C - xprev.Q.C;
        EACH(SB)
#undef SB
        float dxa = xca - xpa;
        float dxb = xcb - xpb;
        float2 dj = make_float2(xcj.x - xpj.x, xcj.y - xpj.y);

        float U2 = fmaf(dxb, fmaf(dxa, 1.f/24.f, A1a * (1.f/6.f)), 0.5f * A2);
        float V2 = fmaf(dxb, fmaf(dxa, 1.f/6.f, A1a * 0.5f), A2);
        float h2 = fmaf(dxa, 0.5f, A1a);
        float u30 = fmaf(dj.x, U2, A3p.x);
        float u31 = fmaf(dj.y, U2, A3p.y);
#define AC(Q,C) { ac0.Q.C = fmaf(u30, dxv.Q.C, ac0.Q.C); \
                  ac1.Q.C = fmaf(u31, dxv.Q.C, ac1.Q.C); }
        EACH(AC)
#undef AC
        A3p.x = fmaf(dj.x, V2, A3p.x);
        A3p.y = fmaf(dj.y, V2, A3p.y);
        if (h == 0) {
#define CS(Q,C) A3f.Q.C = fmaf(dxv.Q.C, V2, A3f.Q.C);
            EACH(CS)
#undef CS
        }
        A2 = fmaf(dxb, h2, A2);
        A1a += dxa;

        xprev = xc; xpa = xca; xpb = xcb; xpj = xcj;
    }

    if (ATOMIC) {
        float* o = dst + t * 256 + (h * 2) * 16;
#define STA(Q,C,K) atomicAdd(o + (K), ac0.Q.C); atomicAdd(o + 16 + (K), ac1.Q.C);
        STA(a,x,0) STA(a,y,1) STA(a,z,2) STA(a,w,3)
        STA(b,x,4) STA(b,y,5) STA(b,z,6) STA(b,w,7)
        STA(c,x,8) STA(c,y,9) STA(c,z,10) STA(c,w,11)
        STA(d,x,12) STA(d,y,13) STA(d,z,14) STA(d,w,15)
#undef STA
    } else {
        float* o = dst + (size_t)cb * L4 + t * 256 + (h * 2) * 16;
        stv16(o, ac0);
        stv16(o + 16, ac1);
    }

    if (h == 0) {
        float* o = chunk_sig + (size_t)cb * SIG13;
        if (ib == 0) o[ia] = A1a;
        o[16 + t] = A2;
        stv16(o + 272 + t * 16, A3f);
    }
}

// ===== K2: fused prefix-cascade + correction + reduce (single loop) =====
// (R22-proven structure; prefetch deepened 4 -> 8 to cover L2 latency.)
template <bool HAVE_PART>
__global__ __launch_bounds__(256, 1) void k_fuse(const float* __restrict__ partials,
                                                 const float* __restrict__ chunk_sig,
                                                 float* __restrict__ out13,
                                                 float* __restrict__ out4) {
    const int a = blockIdx.x;      // 0..15
    const int b = blockIdx.y;      // 0..15
    const int t = threadIdx.x;     // j*16 + d
    const int j = t >> 4, d = t & 15;
    const int e = a * 4096 + b * 256 + t;

    float P1 = 0.f, P2 = 0.f, P3 = 0.f, acc = 0.f;

    // 8-deep statically-named prefetch (rule #20)
#define DECL(J) float s1a_##J, s1b_##J, s1j_##J, l2ab_##J, l2bj_##J, l2jd_##J, \
                      l3abj_##J, l3bjd_##J, l1d_##J, pt_##J;
    DECL(0) DECL(1) DECL(2) DECL(3) DECL(4) DECL(5) DECL(6) DECL(7)
#undef DECL
#define PLOAD(J, C) { int cc = (C) < NC ? (C) : NC - 1; \
    const float* B = chunk_sig + (size_t)cc * SIG13; \
    s1a_##J = B[a]; s1b_##J = B[b]; s1j_##J = B[j]; l1d_##J = B[d]; \
    l2ab_##J = B[16 + a * 16 + b]; \
    l2bj_##J = B[16 + b * 16 + j]; \
    l2jd_##J = B[16 + t]; \
    l3abj_##J = B[272 + a * 256 + b * 16 + j]; \
    l3bjd_##J = B[272 + b * 256 + t]; \
    pt_##J = HAVE_PART ? partials[(size_t)cc * L4 + e] : 0.f; }
    PLOAD(0, 0) PLOAD(1, 1) PLOAD(2, 2) PLOAD(3, 3)
    PLOAD(4, 4) PLOAD(5, 5) PLOAD(6, 6) PLOAD(7, 7)

    for (int c0 = 0; c0 < NC; c0 += 8) {
#define PSTEP(J) { int c = c0 + J; \
        acc += pt_##J + fmaf(P1, l3bjd_##J, fmaf(P2, l2jd_##J, P3 * l1d_##J)); \
        P3 += l3abj_##J + fmaf(P1, l2bj_##J, P2 * s1j_##J); \
        P2 += l2ab_##J + P1 * s1b_##J; \
        P1 += s1a_##J; \
        PLOAD(J, c + 8) }
        PSTEP(0) PSTEP(1) PSTEP(2) PSTEP(3)
        PSTEP(4) PSTEP(5) PSTEP(6) PSTEP(7)
#undef PSTEP
    }
#undef PLOAD

    // levels 1-3 finals (inclusive prefixes)
    if (b == 0 && t == 0) out13[a] = P1;
    if (t == 0) out13[16 + a * 16 + b] = P2;
    if (d == 0) out13[272 + a * 256 + b * 16 + j] = P3;

    if (HAVE_PART) out4[e] = acc;
    else           out4[e] += acc;   // local-L4 already atomically accumulated
}

extern "C" void kernel_launch(void* const* d_in, const int* in_sizes, int n_in,
                              void* d_out, int out_size, void* d_ws, size_t ws_size,
                              hipStream_t stream) {
    const float* x = (const float*)d_in[0];
    float* out = (float*)d_out;
    float* ws = (float*)d_ws;

    float* chunk_sig = ws;                               // NC * SIG13
    float* partials = chunk_sig + (size_t)NC * SIG13;    // NC * L4
    const size_t need_bytes =
        ((size_t)NC * SIG13 + (size_t)NC * L4) * sizeof(float);

    if (ws_size >= need_bytes) {
        k_local4<false><<<dim3(NC, 8), dim3(256), 0, stream>>>(x, chunk_sig, partials);
        k_fuse<true><<<dim3(16, 16), dim3(256), 0, stream>>>(partials, chunk_sig,
                                                             out, out + SIG13);
    } else {
        hipMemsetAsync(out + SIG13, 0, (size_t)L4 * sizeof(float), stream);
        k_local4<true><<<dim3(NC, 8), dim3(256), 0, stream>>>(x, chunk_sig, out + SIG13);
        k_fuse<false><<<dim3(16, 16), dim3(256), 0, stream>>>(nullptr, chunk_sig,
                                                              out, out + SIG13);
    }
}

// Round 25
// 43.451 us; speedup vs baseline: 1.1066x; 1.0022x over previous
//
#include <hip/hip_runtime.h>

#define DIMV 16
#define NSTEP 4095      // 4096 - 1 increments
#define NC 64           // chunks
#define TSTEP 64        // chunk length
#define SIG13 4368      // 16 + 256 + 4096
#define L4 65536        // 16^4

// 16-wide register vector as explicit float4s — never runtime-indexed (rule #20).
struct V16 { float4 a, b, c, d; };

#define EACH(OP) OP(a,x) OP(a,y) OP(a,z) OP(a,w) OP(b,x) OP(b,y) OP(b,z) OP(b,w) \
                 OP(c,x) OP(c,y) OP(c,z) OP(c,w) OP(d,x) OP(d,y) OP(d,z) OP(d,w)

__device__ inline V16 ldv16(const float* p) {
    const float4* q = reinterpret_cast<const float4*>(p);
    V16 v; v.a = q[0]; v.b = q[1]; v.c = q[2]; v.d = q[3]; return v;
}
__device__ inline void stv16(float* p, const V16& v) {
    float4* q = reinterpret_cast<float4*>(p);
    q[0] = v.a; q[1] = v.b; q[2] = v.c; q[3] = v.d;
}
__device__ inline V16 zerov16() {
    V16 v; v.a = v.b = v.c = v.d = make_float4(0.f, 0.f, 0.f, 0.f); return v;
}

// ===== K1: chunk-LOCAL level-4 scan (from zero; no dependencies) =====
// (R22-proven body.) block (cb, h): chunk cb, j-pair (2h, 2h+1). Stages the
// x-chunk into LDS, computes dx in registers, runs the 64-step local recurrence.
// h==0 blocks also write the levels-1..3 chunk signature.
// CHANGE vs R24: partials layout is now [c][h][t][32] so each thread's 32
// accumulator floats are CONTIGUOUS -> wave writes one 8 KB burst (was a
// 64-line scatter using 32B/64B-line = 2x write amplification).
template <bool ATOMIC>
__global__ __launch_bounds__(256, 1) void k_local4(const float* __restrict__ x,
                                                   float* __restrict__ chunk_sig,
                                                   float* __restrict__ dst) {
    __shared__ float sx[(TSTEP + 1) * DIMV];   // 4.16 KB
    const int cb = blockIdx.x;   // 0..NC-1
    const int h = blockIdx.y;    // 0..7 : j-pair
    const int t = threadIdx.x;
    const int ia = t >> 4, ib = t & 15;

    const int s0 = cb * TSTEP;
    const int s1 = (s0 + TSTEP < NSTEP) ? (s0 + TSTEP) : NSTEP;
    const int nrow = s1 - s0;                  // 64 (63 for last chunk)

    {
        const float4* src = reinterpret_cast<const float4*>(x + (size_t)s0 * DIMV);
        float4* sd4 = reinterpret_cast<float4*>(sx);
        const int nslot = (nrow + 1) * (DIMV / 4);   // <= 260
        if (t < nslot) sd4[t] = src[t];
        int slot2 = t + 256;
        if (slot2 < nslot) sd4[slot2] = src[slot2];
    }
    __syncthreads();

    float A1a = 0.f, A2 = 0.f;
    float2 A3p = make_float2(0.f, 0.f);
    V16 A3f = zerov16();                       // full level-3 (used when h==0)
    V16 ac0 = zerov16(), ac1 = zerov16();

    V16 xprev = ldv16(sx);
    float xpa = sx[ia], xpb = sx[ib];
    float2 xpj = *reinterpret_cast<const float2*>(sx + 2 * h);

    for (int si = 0; si < nrow; ++si) {
        const float* nr = sx + (si + 1) * DIMV;
        V16 xc = ldv16(nr);                    // wave-uniform -> LDS broadcast
        float xca = nr[ia];
        float xcb = nr[ib];
        float2 xcj = *reinterpret_cast<const float2*>(nr + 2 * h);

        V16 dxv;
#define SB(Q,C) dxv.Q.C = xc.Q.C - xprev.Q.C;
        EACH(SB)
#undef SB
        float dxa = xca - xpa;
        float dxb = xcb - xpb;
        float2 dj = make_float2(xcj.x - xpj.x, xcj.y - xpj.y);

        float U2 = fmaf(dxb, fmaf(dxa, 1.f/24.f, A1a * (1.f/6.f)), 0.5f * A2);
        float V2 = fmaf(dxb, fmaf(dxa, 1.f/6.f, A1a * 0.5f), A2);
        float h2 = fmaf(dxa, 0.5f, A1a);
        float u30 = fmaf(dj.x, U2, A3p.x);
        float u31 = fmaf(dj.y, U2, A3p.y);
#define AC(Q,C) { ac0.Q.C = fmaf(u30, dxv.Q.C, ac0.Q.C); \
                  ac1.Q.C = fmaf(u31, dxv.Q.C, ac1.Q.C); }
        EACH(AC)
#undef AC
        A3p.x = fmaf(dj.x, V2, A3p.x);
        A3p.y = fmaf(dj.y, V2, A3p.y);
        if (h == 0) {
#define CS(Q,C) A3f.Q.C = fmaf(dxv.Q.C, V2, A3f.Q.C);
            EACH(CS)
#undef CS
        }
        A2 = fmaf(dxb, h2, A2);
        A1a += dxa;

        xprev = xc; xpa = xca; xpb = xcb; xpj = xcj;
    }

    if (ATOMIC) {
        // fallback keeps standard e-order (writes directly into out4)
        float* o = dst + t * 256 + (h * 2) * 16;
#define STA(Q,C,K) atomicAdd(o + (K), ac0.Q.C); atomicAdd(o + 16 + (K), ac1.Q.C);
        STA(a,x,0) STA(a,y,1) STA(a,z,2) STA(a,w,3)
        STA(b,x,4) STA(b,y,5) STA(b,z,6) STA(b,w,7)
        STA(c,x,8) STA(c,y,9) STA(c,z,10) STA(c,w,11)
        STA(d,x,12) STA(d,y,13) STA(d,z,14) STA(d,w,15)
#undef STA
    } else {
        // coalesced layout: [c][h][t][32]
        float* o = dst + (size_t)cb * L4 + h * 8192 + t * 32;
        stv16(o, ac0);
        stv16(o + 16, ac1);
    }

    if (h == 0) {
        float* o = chunk_sig + (size_t)cb * SIG13;
        if (ib == 0) o[ia] = A1a;
        o[16 + t] = A2;
        stv16(o + 272 + t * 16, A3f);
    }
}

// ===== K2: fused prefix-cascade + correction + reduce (single loop) =====
// (R22/R24-proven; partials read index adapted to the [c][h][t][32] layout:
// element e=(a,b,j,d) lives at (j>>1)*8192 + (a*16+b)*32 + (j&1)*16 + d.)
template <bool HAVE_PART>
__global__ __launch_bounds__(256, 1) void k_fuse(const float* __restrict__ partials,
                                                 const float* __restrict__ chunk_sig,
                                                 float* __restrict__ out13,
                                                 float* __restrict__ out4) {
    const int a = blockIdx.x;      // 0..15
    const int b = blockIdx.y;      // 0..15
    const int t = threadIdx.x;     // j*16 + d
    const int j = t >> 4, d = t & 15;
    const int e = a * 4096 + b * 256 + t;
    // transposed partials index: (t>>5)=j>>1, (t&31)=(j&1)*16+d
    const int pidx = (t >> 5) * 8192 + (a * 16 + b) * 32 + (t & 31);

    float P1 = 0.f, P2 = 0.f, P3 = 0.f, acc = 0.f;

    // 8-deep statically-named prefetch (rule #20)
#define DECL(J) float s1a_##J, s1b_##J, s1j_##J, l2ab_##J, l2bj_##J, l2jd_##J, \
                      l3abj_##J, l3bjd_##J, l1d_##J, pt_##J;
    DECL(0) DECL(1) DECL(2) DECL(3) DECL(4) DECL(5) DECL(6) DECL(7)
#undef DECL
#define PLOAD(J, C) { int cc = (C) < NC ? (C) : NC - 1; \
    const float* B = chunk_sig + (size_t)cc * SIG13; \
    s1a_##J = B[a]; s1b_##J = B[b]; s1j_##J = B[j]; l1d_##J = B[d]; \
    l2ab_##J = B[16 + a * 16 + b]; \
    l2bj_##J = B[16 + b * 16 + j]; \
    l2jd_##J = B[16 + t]; \
    l3abj_##J = B[272 + a * 256 + b * 16 + j]; \
    l3bjd_##J = B[272 + b * 256 + t]; \
    pt_##J = HAVE_PART ? partials[(size_t)cc * L4 + pidx] : 0.f; }
    PLOAD(0, 0) PLOAD(1, 1) PLOAD(2, 2) PLOAD(3, 3)
    PLOAD(4, 4) PLOAD(5, 5) PLOAD(6, 6) PLOAD(7, 7)

    for (int c0 = 0; c0 < NC; c0 += 8) {
#define PSTEP(J) { int c = c0 + J; \
        acc += pt_##J + fmaf(P1, l3bjd_##J, fmaf(P2, l2jd_##J, P3 * l1d_##J)); \
        P3 += l3abj_##J + fmaf(P1, l2bj_##J, P2 * s1j_##J); \
        P2 += l2ab_##J + P1 * s1b_##J; \
        P1 += s1a_##J; \
        PLOAD(J, c + 8) }
        PSTEP(0) PSTEP(1) PSTEP(2) PSTEP(3)
        PSTEP(4) PSTEP(5) PSTEP(6) PSTEP(7)
#undef PSTEP
    }
#undef PLOAD

    // levels 1-3 finals (inclusive prefixes)
    if (b == 0 && t == 0) out13[a] = P1;
    if (t == 0) out13[16 + a * 16 + b] = P2;
    if (d == 0) out13[272 + a * 256 + b * 16 + j] = P3;

    if (HAVE_PART) out4[e] = acc;
    else           out4[e] += acc;   // local-L4 already atomically accumulated
}

extern "C" void kernel_launch(void* const* d_in, const int* in_sizes, int n_in,
                              void* d_out, int out_size, void* d_ws, size_t ws_size,
                              hipStream_t stream) {
    const float* x = (const float*)d_in[0];
    float* out = (float*)d_out;
    float* ws = (float*)d_ws;

    float* chunk_sig = ws;                               // NC * SIG13
    float* partials = chunk_sig + (size_t)NC * SIG13;    // NC * L4
    const size_t need_bytes =
        ((size_t)NC * SIG13 + (size_t)NC * L4) * sizeof(float);

    if (ws_size >= need_bytes) {
        k_local4<false><<<dim3(NC, 8), dim3(256), 0, stream>>>(x, chunk_sig, partials);
        k_fuse<true><<<dim3(16, 16), dim3(256), 0, stream>>>(partials, chunk_sig,
                                                             out, out + SIG13);
    } else {
        hipMemsetAsync(out + SIG13, 0, (size_t)L4 * sizeof(float), stream);
        k_local4<true><<<dim3(NC, 8), dim3(256), 0, stream>>>(x, chunk_sig, out + SIG13);
        k_fuse<false><<<dim3(16, 16), dim3(256), 0, stream>>>(nullptr, chunk_sig,
                                                              out, out + SIG13);
    }
}